// Round 2
// baseline (249.125 us; speedup 1.0000x reference)
//
#include <hip/hip_runtime.h>

// ALSTM: adaptive-computation-time LSTM.
// Key facts exploited:
//  - sum(w) == 1  =>  output = (w@H)@W_out^T + b_out ; only hbar/cbar needed
//    (no H/C history is ever materialized).
//  - steps after the halting step have w == 0 and cannot affect n  =>
//    data-dependent early exit is exact (b_halt=1 => halts at t~1).
// Plain launch (256 blocks x 256 thr, 1 block/CU) + software grid barrier in
// d_ws (agent-scope atomics) -- hipLaunchCooperativeKernel failed silently in
// this harness (R1 post-mortem: output buffer bit-identical to stub round).

#define HID    2048
#define INS    1024
#define OUTS   1024
#define MSTEPS 100
#define NBLK   256
#define NTHR   256
#define JPB    8      // hidden units owned per block (256*8 = 2048)

__device__ __forceinline__ float wave_reduce(float v) {
    #pragma unroll
    for (int off = 32; off > 0; off >>= 1)
        v += __shfl_down(v, off, 64);
    return v;  // lane 0 holds the sum
}

// ws layout (floats): [0..128) halt-dot slots | [128] barrier counter (u32,
// own cache line via padding) | [256..256+2048) h_glob | then hbar_g.
// kernel_launch memsets the first 1024 bytes to 0 each call.

__global__ __launch_bounds__(NTHR) void alstm_kernel(
    const float* __restrict__ x,      const float* __restrict__ h0,
    const float* __restrict__ c0,     const float* __restrict__ W_ih,
    const float* __restrict__ b_ih,   const float* __restrict__ W_hh,
    const float* __restrict__ b_hh,   const float* __restrict__ w_halt,
    const float* __restrict__ b_halt, const float* __restrict__ W_out,
    const float* __restrict__ b_out,  float* __restrict__ out,
    float* __restrict__ ws)
{
    const int b    = blockIdx.x;
    const int tid  = threadIdx.x;
    const int wave = tid >> 6;
    const int lane = tid & 63;

    float*    slots  = ws;                  // [128] halt-dot accumulators
    unsigned* bar    = (unsigned*)(ws + 128);
    float*    h_glob = ws + 256;            // [2048] current h
    float*    hbar_g = ws + 256 + HID;      // [2048] pooled h

    unsigned bar_target = 0;
    // Software grid barrier: monotone counter, agent scope (crosses XCD L2s).
    #define GBAR() do {                                                        \
        __syncthreads();                                                       \
        if (tid == 0) {                                                        \
            bar_target += NBLK;                                                \
            __hip_atomic_fetch_add(bar, 1u, __ATOMIC_ACQ_REL,                  \
                                   __HIP_MEMORY_SCOPE_AGENT);                  \
            while (__hip_atomic_load(bar, __ATOMIC_ACQUIRE,                    \
                                     __HIP_MEMORY_SCOPE_AGENT) < bar_target)   \
                __builtin_amdgcn_s_sleep(1);                                   \
        }                                                                      \
        __syncthreads();                                                       \
    } while (0)

    __shared__ float h_lds[HID];
    __shared__ float gate_lds[4 * JPB];
    __shared__ float ihx_lds[4 * JPB];
    __shared__ float wflag_lds[4 * JPB];

    const float bh = b_halt[0];
    const int j_own = b * JPB + tid;        // valid when tid < JPB

    // ------------- prologue: ih_x for this block's 32 gate-rows -------------
    for (int k = tid; k < INS; k += NTHR) h_lds[k] = x[k];
    __syncthreads();

    for (int jj = 0; jj < JPB; ++jj) {
        int r = wave * HID + b * JPB + jj;
        const float* wrow = W_ih + (size_t)r * (INS + 1);
        float acc = 0.f;
        for (int k = lane; k < INS; k += 64) acc += wrow[1 + k] * h_lds[k];
        acc = wave_reduce(acc);
        if (lane == 0) {
            ihx_lds[wave * JPB + jj]   = acc + b_ih[r] + b_hh[r];
            wflag_lds[wave * JPB + jj] = wrow[0];
        }
    }

    float c_reg = 0.f, h_reg = 0.f, hbar = 0.f, cbar = 0.f;
    if (tid < JPB) c_reg = c0[j_own];

    // ------------- recurrence with online halting -------------
    float csum = 0.f, r_halt = 0.f;
    int   n_halt = 0;
    for (int t = 0; t <= MSTEPS; ++t) {
        __syncthreads();                    // h_lds reuse
        const float* hsrc = (t == 0) ? h0 : h_glob;
        for (int k = tid; k < HID; k += NTHR) h_lds[k] = hsrc[k];
        __syncthreads();

        // 8 gate-rows per wave (rows wave*2048 + b*8 + jj of W_hh)
        {
            const float* wbase = W_hh + (size_t)(wave * HID + b * JPB) * HID;
            const float4* hv = (const float4*)h_lds;
            float acc[JPB];
            #pragma unroll
            for (int jj = 0; jj < JPB; ++jj) acc[jj] = 0.f;
            #pragma unroll
            for (int m = 0; m < HID / 256; ++m) {
                float4 hh = hv[lane + 64 * m];
                #pragma unroll
                for (int jj = 0; jj < JPB; ++jj) {
                    float4 wv = ((const float4*)(wbase + (size_t)jj * HID))[lane + 64 * m];
                    acc[jj] += wv.x * hh.x + wv.y * hh.y + wv.z * hh.z + wv.w * hh.w;
                }
            }
            #pragma unroll
            for (int jj = 0; jj < JPB; ++jj) {
                float s = wave_reduce(acc[jj]);
                if (lane == 0) {
                    float base = ihx_lds[wave * JPB + jj];
                    if (t == 0) base += wflag_lds[wave * JPB + jj];
                    gate_lds[wave * JPB + jj] = base + s;
                }
            }
        }
        __syncthreads();

        float part = 0.f;
        if (tid < JPB) {
            float iv = gate_lds[0 * JPB + tid];
            float fv = gate_lds[1 * JPB + tid];
            float gv = gate_lds[2 * JPB + tid];
            float ov = gate_lds[3 * JPB + tid];
            iv = 1.f / (1.f + expf(-iv));
            fv = 1.f / (1.f + expf(-fv));
            gv = tanhf(gv);
            ov = 1.f / (1.f + expf(-ov));
            c_reg = fv * c_reg + iv * gv;
            h_reg = ov * tanhf(c_reg);
            h_glob[j_own] = h_reg;
            part = h_reg * w_halt[j_own];
        }
        part += __shfl_down(part, 4, 64);
        part += __shfl_down(part, 2, 64);
        part += __shfl_down(part, 1, 64);
        if (tid == 0) atomicAdd(&slots[t], part);   // device-scope by default

        GBAR();   // h_glob + slots[t] globally visible

        float dotv = __hip_atomic_load(&slots[t], __ATOMIC_RELAXED,
                                       __HIP_MEMORY_SCOPE_AGENT);
        float p = 1.f / (1.f + expf(-(dotv + bh)));
        float prev = csum;
        csum += p;
        bool halt_now = (csum >= 1.f - 0.01f) || (t == MSTEPS);
        float wt = halt_now ? (1.f - prev) : p;
        if (tid < JPB) { hbar += wt * h_reg; cbar += wt * c_reg; }
        if (halt_now) { n_halt = t; r_halt = 1.f - prev; break; }  // uniform
    }

    // ------------- epilogue -------------
    if (tid < JPB) {
        out[OUTS + j_own]       = hbar;   // h_out
        out[OUTS + HID + j_own] = cbar;   // c_out
        hbar_g[j_own] = hbar;
    }
    if (b == 0 && tid == 0) out[OUTS + 2 * HID] = (float)(n_halt + 1) + r_halt;

    GBAR();   // hbar_g visible

    for (int k = tid; k < HID; k += NTHR) h_lds[k] = hbar_g[k];
    __syncthreads();

    // output = W_out @ hbar + b_out : one wave per row (256 blocks * 4 waves)
    {
        int row = b * 4 + wave;
        const float4* wrow = (const float4*)(W_out + (size_t)row * HID);
        const float4* hv   = (const float4*)h_lds;
        float acc = 0.f;
        #pragma unroll
        for (int m = 0; m < HID / 256; ++m) {
            float4 wv = wrow[lane + 64 * m];
            float4 hh = hv[lane + 64 * m];
            acc += wv.x * hh.x + wv.y * hh.y + wv.z * hh.z + wv.w * hh.w;
        }
        acc = wave_reduce(acc);
        if (lane == 0) out[row] = acc + b_out[row];
    }
    #undef GBAR
}

extern "C" void kernel_launch(void* const* d_in, const int* in_sizes, int n_in,
                              void* d_out, int out_size, void* d_ws, size_t ws_size,
                              hipStream_t stream) {
    const float* x      = (const float*)d_in[0];
    const float* h0     = (const float*)d_in[1];
    const float* c0     = (const float*)d_in[2];
    const float* W_ih   = (const float*)d_in[3];
    const float* b_ih   = (const float*)d_in[4];
    const float* W_hh   = (const float*)d_in[5];
    const float* b_hh   = (const float*)d_in[6];
    const float* w_halt = (const float*)d_in[7];
    const float* b_halt = (const float*)d_in[8];
    const float* W_out  = (const float*)d_in[9];
    const float* b_out  = (const float*)d_in[10];
    float* out = (float*)d_out;
    float* ws  = (float*)d_ws;

    // Zero halt slots + barrier counter (ws is poisoned 0xAA by the harness).
    hipMemsetAsync(d_ws, 0, 1024, stream);

    alstm_kernel<<<dim3(NBLK), dim3(NTHR), 0, stream>>>(
        x, h0, c0, W_ih, b_ih, W_hh, b_hh, w_halt, b_halt, W_out, b_out,
        out, ws);
}

// Round 3
// 189.856 us; speedup vs baseline: 1.3122x; 1.3122x over previous
//
#include <hip/hip_runtime.h>

// ALSTM: adaptive-computation-time LSTM.
//  - sum(w)==1  =>  output = (w@H)@W_out^T + b_out ; only hbar/cbar needed.
//  - steps after halting have w==0 and cannot affect n => early exit exact
//    (b_halt=1 => p0~0.73, halts at t=1: only 2 of 101 steps run).
// R2 post-mortem: latency-bound at 4 waves/CU (Occupancy 11.5%, VALU 2.3%,
// 1.2 TB/s aggregate). R3: 1024 thr/block = 16 waves/CU for 4x MLP.

#define HID    2048
#define INS    1024
#define OUTS   1024
#define MSTEPS 100
#define NBLK   256
#define NTHR   1024
#define NWAVE  16
#define JPB    8      // hidden units owned per block (256*8 = 2048)
#define RPB    32     // gate rows per block (4 gates * JPB)

__device__ __forceinline__ float wave_reduce(float v) {
    #pragma unroll
    for (int off = 32; off > 0; off >>= 1)
        v += __shfl_down(v, off, 64);
    return v;  // lane 0 holds the sum
}

// ws layout (floats): [0..128) halt-dot slots | [128] barrier counter |
// [256..256+2048) h_glob | [256+2048 ..) hbar_g.
// kernel_launch zeroes the first 1024 bytes each call.

__global__ __launch_bounds__(NTHR) void alstm_kernel(
    const float* __restrict__ x,      const float* __restrict__ h0,
    const float* __restrict__ c0,     const float* __restrict__ W_ih,
    const float* __restrict__ b_ih,   const float* __restrict__ W_hh,
    const float* __restrict__ b_hh,   const float* __restrict__ w_halt,
    const float* __restrict__ b_halt, const float* __restrict__ W_out,
    const float* __restrict__ b_out,  float* __restrict__ out,
    float* __restrict__ ws)
{
    const int b    = blockIdx.x;
    const int tid  = threadIdx.x;
    const int wave = tid >> 6;
    const int lane = tid & 63;

    float*    slots  = ws;                  // [128] halt-dot accumulators
    unsigned* bar    = (unsigned*)(ws + 128);
    float*    h_glob = ws + 256;            // [2048] current h
    float*    hbar_g = ws + 256 + HID;      // [2048] pooled h

    unsigned bar_target = 0;
    #define GBAR() do {                                                        \
        __syncthreads();                                                       \
        if (tid == 0) {                                                        \
            bar_target += NBLK;                                                \
            __hip_atomic_fetch_add(bar, 1u, __ATOMIC_ACQ_REL,                  \
                                   __HIP_MEMORY_SCOPE_AGENT);                  \
            while (__hip_atomic_load(bar, __ATOMIC_ACQUIRE,                    \
                                     __HIP_MEMORY_SCOPE_AGENT) < bar_target)   \
                __builtin_amdgcn_s_sleep(1);                                   \
        }                                                                      \
        __syncthreads();                                                       \
    } while (0)

    __shared__ float h_lds[HID];
    __shared__ float gate_lds[RPB];
    __shared__ float ihx_lds[RPB];
    __shared__ float wflag_lds[RPB];
    __shared__ float psum[NWAVE];

    const float bh = b_halt[0];
    const int j_own = b * JPB + tid;        // valid when tid < JPB

    // Local rows for this wave: lr0, lr0+1 (same gate group since lr0 even)
    const int lr0 = 2 * wave;
    const int g   = lr0 >> 3;               // gate 0..3
    const int jj0 = lr0 & 7;                // unit offset 0..7 (and +1)
    const int r0  = g * HID + b * JPB + jj0;  // global gate-row (and r0+1)

    // ------------- prologue: ih_x (W_ih[:,1:]@x + b_ih + b_hh) -------------
    for (int k = tid; k < INS; k += NTHR) h_lds[k] = x[k];
    __syncthreads();

    #pragma unroll
    for (int rr = 0; rr < 2; ++rr) {
        const int r = r0 + rr;
        const float* wrow = W_ih + (size_t)r * (INS + 1) + 1;  // payload, 1024
        const int mis = (r + 1) & 3;        // (r*1025+1) % 4
        const int p0  = (4 - mis) & 3;      // head scalars to peel
        const int nv  = (INS - p0) >> 2;    // aligned float4 count
        const float4* wv = (const float4*)(wrow + p0);
        float acc = 0.f;
        for (int i = lane; i < nv; i += 64) {
            float4 w4 = wv[i];
            int k = p0 + 4 * i;
            acc += w4.x * h_lds[k] + w4.y * h_lds[k + 1]
                 + w4.z * h_lds[k + 2] + w4.w * h_lds[k + 3];
        }
        if (lane == 0) {
            for (int k = 0; k < p0; ++k)            acc += wrow[k] * h_lds[k];
            for (int k = p0 + 4 * nv; k < INS; ++k) acc += wrow[k] * h_lds[k];
        }
        acc = wave_reduce(acc);
        if (lane == 0) {
            ihx_lds[lr0 + rr]   = acc + b_ih[r] + b_hh[r];
            wflag_lds[lr0 + rr] = W_ih[(size_t)r * (INS + 1)];
        }
    }

    float c_reg = 0.f, h_reg = 0.f, hbar = 0.f, cbar = 0.f;
    if (tid < JPB) c_reg = c0[j_own];

    // ------------- recurrence with online halting -------------
    float csum = 0.f, r_halt = 0.f;
    int   n_halt = 0;
    const float4* wrow0 = (const float4*)(W_hh + (size_t)r0 * HID);
    const float4* wrow1 = (const float4*)(W_hh + (size_t)(r0 + 1) * HID);

    for (int t = 0; t <= MSTEPS; ++t) {
        __syncthreads();                    // h_lds reuse
        const float* hsrc = (t == 0) ? h0 : h_glob;
        for (int k = tid; k < HID; k += NTHR) h_lds[k] = hsrc[k];
        __syncthreads();

        // 2 gate-rows per wave, 16 independent global float4 streams
        {
            const float4* hv = (const float4*)h_lds;
            float acc0 = 0.f, acc1 = 0.f;
            #pragma unroll
            for (int m = 0; m < HID / 256; ++m) {
                float4 hh = hv[lane + 64 * m];
                float4 w0 = wrow0[lane + 64 * m];
                float4 w1 = wrow1[lane + 64 * m];
                acc0 += w0.x * hh.x + w0.y * hh.y + w0.z * hh.z + w0.w * hh.w;
                acc1 += w1.x * hh.x + w1.y * hh.y + w1.z * hh.z + w1.w * hh.w;
            }
            acc0 = wave_reduce(acc0);
            acc1 = wave_reduce(acc1);
            if (lane == 0) {
                float b0 = ihx_lds[lr0], b1 = ihx_lds[lr0 + 1];
                if (t == 0) { b0 += wflag_lds[lr0]; b1 += wflag_lds[lr0 + 1]; }
                gate_lds[lr0]     = b0 + acc0;
                gate_lds[lr0 + 1] = b1 + acc1;
            }
        }
        __syncthreads();

        float part = 0.f;
        if (tid < JPB) {
            float iv = gate_lds[0 * JPB + tid];
            float fv = gate_lds[1 * JPB + tid];
            float gv = gate_lds[2 * JPB + tid];
            float ov = gate_lds[3 * JPB + tid];
            iv = 1.f / (1.f + expf(-iv));
            fv = 1.f / (1.f + expf(-fv));
            gv = tanhf(gv);
            ov = 1.f / (1.f + expf(-ov));
            c_reg = fv * c_reg + iv * gv;
            h_reg = ov * tanhf(c_reg);
            h_glob[j_own] = h_reg;
            part = h_reg * w_halt[j_own];
        }
        part += __shfl_down(part, 4, 64);
        part += __shfl_down(part, 2, 64);
        part += __shfl_down(part, 1, 64);
        if (tid == 0) atomicAdd(&slots[t], part);   // device-scope

        GBAR();   // h_glob + slots[t] globally visible

        float dotv = __hip_atomic_load(&slots[t], __ATOMIC_RELAXED,
                                       __HIP_MEMORY_SCOPE_AGENT);
        float p = 1.f / (1.f + expf(-(dotv + bh)));
        float prev = csum;
        csum += p;
        bool halt_now = (csum >= 1.f - 0.01f) || (t == MSTEPS);
        float wt = halt_now ? (1.f - prev) : p;
        if (tid < JPB) { hbar += wt * h_reg; cbar += wt * c_reg; }
        if (halt_now) { n_halt = t; r_halt = 1.f - prev; break; }  // uniform
    }

    // ------------- epilogue -------------
    if (tid < JPB) {
        out[OUTS + j_own]       = hbar;   // h_out
        out[OUTS + HID + j_own] = cbar;   // c_out
        hbar_g[j_own] = hbar;
    }
    if (b == 0 && tid == 0) out[OUTS + 2 * HID] = (float)(n_halt + 1) + r_halt;

    GBAR();   // hbar_g visible

    for (int k = tid; k < HID; k += NTHR) h_lds[k] = hbar_g[k];
    __syncthreads();

    // output = W_out @ hbar + b_out : 4 rows/block, quarter-row per wave
    {
        const int row = b * 4 + (wave & 3);
        const int q   = wave >> 2;          // quarter 0..3 of the dot
        const float4* wrow = (const float4*)(W_out + (size_t)row * HID) + q * 128;
        const float4* hv   = (const float4*)h_lds + q * 128;
        float acc = 0.f;
        #pragma unroll
        for (int m = 0; m < 2; ++m) {
            float4 wv4 = wrow[lane + 64 * m];
            float4 hh  = hv[lane + 64 * m];
            acc += wv4.x * hh.x + wv4.y * hh.y + wv4.z * hh.z + wv4.w * hh.w;
        }
        acc = wave_reduce(acc);
        if (lane == 0) psum[wave] = acc;
    }
    __syncthreads();
    if (tid < 4) {
        int row = b * 4 + tid;
        float s = psum[tid] + psum[tid + 4] + psum[tid + 8] + psum[tid + 12];
        out[row] = s + b_out[row];
    }
    #undef GBAR
}

extern "C" void kernel_launch(void* const* d_in, const int* in_sizes, int n_in,
                              void* d_out, int out_size, void* d_ws, size_t ws_size,
                              hipStream_t stream) {
    const float* x      = (const float*)d_in[0];
    const float* h0     = (const float*)d_in[1];
    const float* c0     = (const float*)d_in[2];
    const float* W_ih   = (const float*)d_in[3];
    const float* b_ih   = (const float*)d_in[4];
    const float* W_hh   = (const float*)d_in[5];
    const float* b_hh   = (const float*)d_in[6];
    const float* w_halt = (const float*)d_in[7];
    const float* b_halt = (const float*)d_in[8];
    const float* W_out  = (const float*)d_in[9];
    const float* b_out  = (const float*)d_in[10];
    float* out = (float*)d_out;
    float* ws  = (float*)d_ws;

    // Zero halt slots + barrier counter (ws is poisoned 0xAA by the harness).
    hipMemsetAsync(d_ws, 0, 1024, stream);

    alstm_kernel<<<dim3(NBLK), dim3(NTHR), 0, stream>>>(
        x, h0, c0, W_ih, b_ih, W_hh, b_hh, w_halt, b_halt, W_out, b_out,
        out, ws);
}

// Round 4
// 185.038 us; speedup vs baseline: 1.3463x; 1.0260x over previous
//
#include <hip/hip_runtime.h>

// ALSTM: adaptive-computation-time LSTM.
//  - sum(w)==1  =>  output = (w@H)@W_out^T + b_out ; only hbar/cbar needed.
//  - steps after halting have w==0 and cannot affect n => early exit exact
//    (b_halt=1 => p0~0.73, halts at t=1: only 2 of 101 steps run).
// R4: W_hh rows live in REGISTERS (64 VGPR/lane, time-invariant) -> zero
// global weight traffic in the recurrence; one-shot loads dominate.
// h double-buffered in ws (steps are now ~200cy; single buffer would race).

#define HID    2048
#define INS    1024
#define OUTS   1024
#define MSTEPS 100
#define NBLK   256
#define NTHR   1024
#define NWAVE  16
#define JPB    8      // hidden units owned per block (256*8 = 2048)
#define RPB    32     // gate rows per block (4 gates * JPB)

__device__ __forceinline__ float wave_reduce(float v) {
    #pragma unroll
    for (int off = 32; off > 0; off >>= 1)
        v += __shfl_down(v, off, 64);
    return v;  // lane 0 holds the sum
}

// ws layout (floats): [0..128) halt-dot slots | [128] barrier counter |
// [256..2304) h buf0 | [2304..4352) h buf1 | [4352..6400) hbar_g.
// kernel_launch zeroes the first 1024 bytes each call.

__global__ __launch_bounds__(NTHR) void alstm_kernel(
    const float* __restrict__ x,      const float* __restrict__ h0,
    const float* __restrict__ c0,     const float* __restrict__ W_ih,
    const float* __restrict__ b_ih,   const float* __restrict__ W_hh,
    const float* __restrict__ b_hh,   const float* __restrict__ w_halt,
    const float* __restrict__ b_halt, const float* __restrict__ W_out,
    const float* __restrict__ b_out,  float* __restrict__ out,
    float* __restrict__ ws)
{
    const int b    = blockIdx.x;
    const int tid  = threadIdx.x;
    const int wave = tid >> 6;
    const int lane = tid & 63;

    float*    slots  = ws;                  // [128] halt-dot accumulators
    unsigned* bar    = (unsigned*)(ws + 128);
    float*    hbuf0  = ws + 256;            // [2048]
    float*    hbuf1  = ws + 256 + HID;      // [2048]
    float*    hbar_g = ws + 256 + 2 * HID;  // [2048] pooled h

    unsigned bar_target = 0;
    #define GBAR() do {                                                        \
        __syncthreads();                                                       \
        if (tid == 0) {                                                        \
            bar_target += NBLK;                                                \
            __hip_atomic_fetch_add(bar, 1u, __ATOMIC_ACQ_REL,                  \
                                   __HIP_MEMORY_SCOPE_AGENT);                  \
            while (__hip_atomic_load(bar, __ATOMIC_ACQUIRE,                    \
                                     __HIP_MEMORY_SCOPE_AGENT) < bar_target)   \
                __builtin_amdgcn_s_sleep(1);                                   \
        }                                                                      \
        __syncthreads();                                                       \
    } while (0)

    __shared__ float h_lds[HID];
    __shared__ float gate_lds[RPB];
    __shared__ float ihx_lds[RPB];
    __shared__ float wflag_lds[RPB];
    __shared__ float psum[NWAVE];

    const float bh = b_halt[0];
    const int j_own = b * JPB + tid;        // valid when tid < JPB

    // Local rows for this wave: lr0, lr0+1
    const int lr0 = 2 * wave;
    const int g   = lr0 >> 3;               // gate 0..3
    const int jj0 = lr0 & 7;                // unit offset
    const int r0  = g * HID + b * JPB + jj0;

    // ---- register prefetch: W_hh (2 rows/wave, 64 VGPR) + W_out slice ----
    float4 w0r[8], w1r[8];
    {
        const float4* wrow0 = (const float4*)(W_hh + (size_t)r0 * HID);
        const float4* wrow1 = (const float4*)(W_hh + (size_t)(r0 + 1) * HID);
        #pragma unroll
        for (int m = 0; m < 8; ++m) {
            w0r[m] = wrow0[lane + 64 * m];
            w1r[m] = wrow1[lane + 64 * m];
        }
    }
    const int orow = b * 4 + (wave & 3);    // W_out row for epilogue
    const int oq   = wave >> 2;             // quarter of the dot
    float4 wo0, wo1;
    {
        const float4* wor = (const float4*)(W_out + (size_t)orow * HID) + oq * 128;
        wo0 = wor[lane];
        wo1 = wor[lane + 64];
    }

    // ------------- prologue: ih_x (W_ih[:,1:]@x + b_ih + b_hh) -------------
    for (int k = tid; k < INS; k += NTHR) h_lds[k] = x[k];
    __syncthreads();

    #pragma unroll
    for (int rr = 0; rr < 2; ++rr) {
        const int r = r0 + rr;
        const float* wrow = W_ih + (size_t)r * (INS + 1) + 1;  // payload, 1024
        const int mis = (r + 1) & 3;
        const int p0  = (4 - mis) & 3;
        const int nv  = (INS - p0) >> 2;
        const float4* wv = (const float4*)(wrow + p0);
        float acc = 0.f;
        for (int i = lane; i < nv; i += 64) {
            float4 w4 = wv[i];
            int k = p0 + 4 * i;
            acc += w4.x * h_lds[k] + w4.y * h_lds[k + 1]
                 + w4.z * h_lds[k + 2] + w4.w * h_lds[k + 3];
        }
        if (lane == 0) {
            for (int k = 0; k < p0; ++k)            acc += wrow[k] * h_lds[k];
            for (int k = p0 + 4 * nv; k < INS; ++k) acc += wrow[k] * h_lds[k];
        }
        acc = wave_reduce(acc);
        if (lane == 0) {
            ihx_lds[lr0 + rr]   = acc + b_ih[r] + b_hh[r];
            wflag_lds[lr0 + rr] = W_ih[(size_t)r * (INS + 1)];
        }
    }

    float c_reg = 0.f, h_reg = 0.f, hbar = 0.f, cbar = 0.f;
    if (tid < JPB) c_reg = c0[j_own];
    __syncthreads();   // h_lds (x) reads done before step-0 staging

    // ------------- recurrence with online halting -------------
    float csum = 0.f, r_halt = 0.f;
    int   n_halt = 0;
    for (int t = 0; t <= MSTEPS; ++t) {
        const float* hsrc = (t == 0) ? h0 : ((t & 1) ? hbuf1 : hbuf0);
        float* hdst = ((t & 1) ? hbuf0 : hbuf1);   // buffer for h_{t+1}
        ((float2*)h_lds)[tid] = ((const float2*)hsrc)[tid];
        __syncthreads();

        // 2 gate-rows per wave, weights in registers, h from LDS
        {
            const float4* hv = (const float4*)h_lds;
            float acc0 = 0.f, acc1 = 0.f;
            #pragma unroll
            for (int m = 0; m < 8; ++m) {
                float4 hh = hv[lane + 64 * m];
                acc0 += w0r[m].x * hh.x + w0r[m].y * hh.y
                      + w0r[m].z * hh.z + w0r[m].w * hh.w;
                acc1 += w1r[m].x * hh.x + w1r[m].y * hh.y
                      + w1r[m].z * hh.z + w1r[m].w * hh.w;
            }
            acc0 = wave_reduce(acc0);
            acc1 = wave_reduce(acc1);
            if (lane == 0) {
                float b0 = ihx_lds[lr0], b1 = ihx_lds[lr0 + 1];
                if (t == 0) { b0 += wflag_lds[lr0]; b1 += wflag_lds[lr0 + 1]; }
                gate_lds[lr0]     = b0 + acc0;
                gate_lds[lr0 + 1] = b1 + acc1;
            }
        }
        __syncthreads();

        float part = 0.f;
        if (tid < JPB) {
            float iv = gate_lds[0 * JPB + tid];
            float fv = gate_lds[1 * JPB + tid];
            float gv = gate_lds[2 * JPB + tid];
            float ov = gate_lds[3 * JPB + tid];
            iv = 1.f / (1.f + expf(-iv));
            fv = 1.f / (1.f + expf(-fv));
            gv = tanhf(gv);
            ov = 1.f / (1.f + expf(-ov));
            c_reg = fv * c_reg + iv * gv;
            h_reg = ov * tanhf(c_reg);
            hdst[j_own] = h_reg;
            part = h_reg * w_halt[j_own];
        }
        part += __shfl_down(part, 4, 64);
        part += __shfl_down(part, 2, 64);
        part += __shfl_down(part, 1, 64);
        if (tid == 0) atomicAdd(&slots[t], part);   // device-scope

        GBAR();   // hdst + slots[t] globally visible; h_lds reads done

        float dotv = __hip_atomic_load(&slots[t], __ATOMIC_RELAXED,
                                       __HIP_MEMORY_SCOPE_AGENT);
        float p = 1.f / (1.f + expf(-(dotv + bh)));
        float prev = csum;
        csum += p;
        bool halt_now = (csum >= 1.f - 0.01f) || (t == MSTEPS);
        float wt = halt_now ? (1.f - prev) : p;
        if (tid < JPB) { hbar += wt * h_reg; cbar += wt * c_reg; }
        if (halt_now) { n_halt = t; r_halt = 1.f - prev; break; }  // uniform
    }

    // ------------- epilogue -------------
    if (tid < JPB) {
        out[OUTS + j_own]       = hbar;   // h_out
        out[OUTS + HID + j_own] = cbar;   // c_out
        hbar_g[j_own] = hbar;
    }
    if (b == 0 && tid == 0) out[OUTS + 2 * HID] = (float)(n_halt + 1) + r_halt;

    GBAR();   // hbar_g visible

    ((float2*)h_lds)[tid] = ((const float2*)hbar_g)[tid];
    __syncthreads();

    // output = W_out @ hbar + b_out : quarter-row per wave, weights in regs
    {
        const float4* hv = (const float4*)h_lds + oq * 128;
        float4 h0v = hv[lane], h1v = hv[lane + 64];
        float acc = wo0.x * h0v.x + wo0.y * h0v.y + wo0.z * h0v.z + wo0.w * h0v.w
                  + wo1.x * h1v.x + wo1.y * h1v.y + wo1.z * h1v.z + wo1.w * h1v.w;
        acc = wave_reduce(acc);
        if (lane == 0) psum[wave] = acc;
    }
    __syncthreads();
    if (tid < 4) {
        int row = b * 4 + tid;
        float s = psum[tid] + psum[tid + 4] + psum[tid + 8] + psum[tid + 12];
        out[row] = s + b_out[row];
    }
    #undef GBAR
}

extern "C" void kernel_launch(void* const* d_in, const int* in_sizes, int n_in,
                              void* d_out, int out_size, void* d_ws, size_t ws_size,
                              hipStream_t stream) {
    const float* x      = (const float*)d_in[0];
    const float* h0     = (const float*)d_in[1];
    const float* c0     = (const float*)d_in[2];
    const float* W_ih   = (const float*)d_in[3];
    const float* b_ih   = (const float*)d_in[4];
    const float* W_hh   = (const float*)d_in[5];
    const float* b_hh   = (const float*)d_in[6];
    const float* w_halt = (const float*)d_in[7];
    const float* b_halt = (const float*)d_in[8];
    const float* W_out  = (const float*)d_in[9];
    const float* b_out  = (const float*)d_in[10];
    float* out = (float*)d_out;
    float* ws  = (float*)d_ws;

    // Zero halt slots + barrier counter (ws is poisoned 0xAA by the harness).
    hipMemsetAsync(d_ws, 0, 1024, stream);

    alstm_kernel<<<dim3(NBLK), dim3(NTHR), 0, stream>>>(
        x, h0, c0, W_ih, b_ih, W_hh, b_hh, w_halt, b_halt, W_out, b_out,
        out, ws);
}